// Round 5
// baseline (131.766 us; speedup 1.0000x reference)
//
#include <hip/hip_runtime.h>
#include <math.h>

#define KM 192
#define NCHUNK 8
#define KCH (KM / NCHUNK)     // 24 objects per chunk
#define EPSF 1e-6f
#define QMIN 0.5f
#define BLK 256
#define H 4
#define TILE (BLK * H)        // 1024 hits per tile

__device__ __forceinline__ float clipb(float b) {
    return fminf(fmaxf(b, 1e-4f), 1.0f - 1e-4f);
}

// ---- K1: per-tile argmax partials into scratch (no global atomics) ----
// pack = (bits(clip(beta)) << 32) | (N-1-i): beta>0 -> bits monotone; low word
// gives jnp.argmax first-index tiebreak. argmax(beta) == argmax(q), monotone.
__global__ void __launch_bounds__(BLK)
k_amax1(const float* __restrict__ beta, const int* __restrict__ tidx,
        unsigned long long* __restrict__ pscr, int N, int HBA) {
    const int e = blockIdx.y;
    __shared__ unsigned long long smax[KM];
    for (int k = threadIdx.x; k < KM; k += BLK) smax[k] = 0ull;
    __syncthreads();
    const size_t base = (size_t)e * N;
    #pragma unroll
    for (int h = 0; h < H; ++h) {
        int i = blockIdx.x * TILE + h * BLK + threadIdx.x;
        if (i < N) {
            int t = tidx[base + i];
            if (t > 0) {
                float bc = clipb(beta[base + i]);
                unsigned long long pack =
                    ((unsigned long long)__float_as_uint(bc) << 32) |
                    (unsigned long long)(unsigned)(N - 1 - i);
                atomicMax(&smax[t], pack);
            }
        }
    }
    __syncthreads();
    unsigned long long* row = pscr + ((size_t)e * HBA + blockIdx.x) * KM;
    for (int k = threadIdx.x; k < KM; k += BLK) row[k] = smax[k];
}

// ---- K2: reduce partials -> alpha table (x, y, q_alpha*valid, beta_alpha);
//          spare blocks zero enm/eden/scal ----
__global__ void __launch_bounds__(BLK)
k_amax2(const unsigned long long* __restrict__ pscr, const float* __restrict__ cc,
        float4* __restrict__ alpha, float* __restrict__ zbase,
        int N, int HBA, int B, int NZ) {
    const int b = blockIdx.x;
    if (b < B * KM) {
        const int ev = b / KM, k = b - ev * KM;
        unsigned long long v = 0ull;
        for (int t = threadIdx.x; t < HBA; t += BLK) {
            unsigned long long p = pscr[((size_t)ev * HBA + t) * KM + k];
            v = (p > v) ? p : v;
        }
        for (int off = 32; off > 0; off >>= 1) {
            unsigned long long o = __shfl_down(v, off);
            v = (o > v) ? o : v;
        }
        __shared__ unsigned long long sw[4];
        if ((threadIdx.x & 63) == 0) sw[threadIdx.x >> 6] = v;
        __syncthreads();
        if (threadIdx.x == 0) {
            unsigned long long a01 = (sw[0] > sw[1]) ? sw[0] : sw[1];
            unsigned long long a23 = (sw[2] > sw[3]) ? sw[2] : sw[3];
            v = (a01 > a23) ? a01 : a23;
            float4 a = make_float4(0.f, 0.f, 0.f, 0.f);
            if (v) {
                int idx  = N - 1 - (int)(unsigned)(v & 0xffffffffull);
                float bc = __uint_as_float((unsigned)(v >> 32));
                float at = atanhf(bc);
                a.x = cc[((size_t)ev * N + idx) * 2 + 0];
                a.y = cc[((size_t)ev * N + idx) * 2 + 1];
                a.z = at * at + QMIN;     // q_alpha; 0 => invalid slot
                a.w = bc;                 // clipped beta_alpha
            }
            alpha[ev * KM + k] = a;
        }
    } else {
        int z = (b - B * KM) * BLK + threadIdx.x;
        if (z < NZ) zbase[z] = 0.f;
    }
}

// ---- K3: main pass, grid (hit-tile, chunk, event), 4 hits/thread ----
__global__ void __launch_bounds__(BLK, 8)
k_main(const float* __restrict__ beta, const float* __restrict__ cc,
       const float* __restrict__ pe,   const float* __restrict__ te,
       const int* __restrict__ tidx,   const float4* __restrict__ alpha,
       float* __restrict__ enm, float* __restrict__ eden,
       float* __restrict__ scal, int N) {
    const int e = blockIdx.z, c = blockIdx.y, k0 = c * KCH;
    __shared__ float4 sa[KCH];
    __shared__ float  sn[KM], sd[KM];
    __shared__ float  sw[12];
    if (threadIdx.x < KCH) sa[threadIdx.x] = alpha[e * KM + k0 + threadIdx.x];
    if (c == 0)
        for (int k = threadIdx.x; k < KM; k += BLK) { sn[k] = 0.f; sd[k] = 0.f; }
    __syncthreads();

    const size_t base = (size_t)e * N;
    const int i0 = blockIdx.x * TILE + threadIdx.x;
    float ax[H], ay[H], qq[H], bcl[H];
    int tt[H];
    #pragma unroll
    for (int h = 0; h < H; ++h) {
        int i = i0 + h * BLK;
        bool ok = i < N;
        int ii = ok ? i : 0;
        float2 cp = ((const float2*)cc)[base + ii];
        ax[h] = cp.x; ay[h] = cp.y;
        float bc = clipb(beta[base + ii]);
        bcl[h] = bc;
        float a = atanhf(bc);
        qq[h] = ok ? (a * a + QMIN) : 0.f;   // qq=0 kills lv of pad hits
        tt[h] = ok ? tidx[base + ii] : 0;
    }

    float acc[H] = {0.f, 0.f, 0.f, 0.f};
    for (int k = 0; k < KCH; ++k) {
        float4 av = sa[k];
        #pragma unroll
        for (int h = 0; h < H; ++h) {
            float dx = ax[h] - av.x, dy = ay[h] - av.y;
            float d2 = fmaf(dx, dx, fmaf(dy, dy, EPSF));
            float s  = __builtin_amdgcn_sqrtf(d2);
            acc[h] = fmaf(fmaxf(1.f - s, 0.f), av.z, acc[h]);
        }
    }

    float lv = 0.f, bn = 0.f, cn = 0.f;
    #pragma unroll
    for (int h = 0; h < H; ++h) {
        int i = i0 + h * BLK;
        bool ok = i < N;
        float rep = acc[h], att = 0.f;
        int tl = tt[h] - k0;
        if (tt[h] > 0 && tl >= 0 && tl < KCH) {
            float4 ao = sa[tl];
            float dx = ax[h] - ao.x, dy = ay[h] - ao.y;
            float d2e = fmaf(dx, dx, fmaf(dy, dy, EPSF));
            rep -= fmaxf(1.f - __builtin_amdgcn_sqrtf(d2e), 0.f) * ao.z;
            att  = fmaf(dx, dx, dy * dy) * ao.z;
        }
        lv += qq[h] * (att + rep);
        if (c == 0 && ok) {
            if (tt[h] > 0) {
                float tev = te[base + i];
                float edv = (pe[base + i] - tev) / (tev + 1.f);
                float ad  = fabsf(edv);
                float eh  = (ad <= 2.f) ? 0.5f * ad * ad : 2.f * (ad - 1.f);
                atomicAdd(&sn[tt[h]], bcl[h] * eh);
                atomicAdd(&sd[tt[h]], bcl[h]);
            } else { bn += bcl[h]; cn += 1.f; }
        }
    }
    __syncthreads();

    if (c == 0) {
        for (int k = threadIdx.x; k < KM; k += BLK) {
            float vd = sd[k];
            if (vd != 0.f) {
                atomicAdd(&enm [e * KM + k], sn[k]);
                atomicAdd(&eden[e * KM + k], vd);
            }
        }
    }
    for (int off = 32; off > 0; off >>= 1) {
        lv += __shfl_down(lv, off);
        bn += __shfl_down(bn, off);
        cn += __shfl_down(cn, off);
    }
    const int wid = threadIdx.x >> 6;
    if ((threadIdx.x & 63) == 0) { sw[wid] = lv; sw[4 + wid] = bn; sw[8 + wid] = cn; }
    __syncthreads();
    if (threadIdx.x == 0) {
        atomicAdd(&scal[e * 8 + 0], (sw[0] + sw[1]) + (sw[2] + sw[3]));
        if (c == 0) {
            atomicAdd(&scal[e * 8 + 3], (sw[4] + sw[5]) + (sw[6] + sw[7]));
            atomicAdd(&scal[e * 8 + 4], (sw[8] + sw[9]) + (sw[10] + sw[11]));
        }
    }
}

// ---- K4: finalize (1 block) ----
__global__ void __launch_bounds__(BLK)
k_fin(const float* __restrict__ enm, const float* __restrict__ eden,
      const float4* __restrict__ alpha, const float* __restrict__ scal,
      float* __restrict__ out, int N, int B) {
    __shared__ float sred[12];
    float tot = 0.f;
    for (int ev = 0; ev < B; ++ev) {
        float lb = 0.f, nv = 0.f, le = 0.f;
        for (int k = threadIdx.x; k < KM; k += BLK) {
            float4 a = alpha[ev * KM + k];
            if (a.z > 0.f) {
                lb += 1.f - a.w;
                nv += 1.f;
                le += enm[ev * KM + k] / (eden[ev * KM + k] + EPSF);
            }
        }
        for (int off = 32; off > 0; off >>= 1) {
            lb += __shfl_down(lb, off);
            nv += __shfl_down(nv, off);
            le += __shfl_down(le, off);
        }
        const int wid = threadIdx.x >> 6;
        if ((threadIdx.x & 63) == 0) { sred[wid] = lb; sred[4 + wid] = nv; sred[8 + wid] = le; }
        __syncthreads();
        if (threadIdx.x == 0) {
            float lbs = (sred[0] + sred[1]) + (sred[2] + sred[3]);
            float nvs = (sred[4] + sred[5]) + (sred[6] + sred[7]);
            float les = (sred[8] + sred[9]) + (sred[10] + sred[11]);
            float nobj = nvs + EPSF;
            tot += scal[ev * 8 + 0] / (float)N + lbs / nobj
                 + scal[ev * 8 + 3] / (scal[ev * 8 + 4] + EPSF) + les / nobj;
        }
        __syncthreads();
    }
    if (threadIdx.x == 0) out[0] = tot / (float)B;
}

extern "C" void kernel_launch(void* const* d_in, const int* in_sizes, int n_in,
                              void* d_out, int out_size, void* d_ws, size_t ws_size,
                              hipStream_t stream) {
    const int B = 4;
    const int N = in_sizes[0] / B;            // beta is [B,N,1]
    const int HBA = (N + TILE - 1) / TILE;    // tiles of 1024

    const float* beta = (const float*)d_in[0];
    const float* cc   = (const float*)d_in[1];
    const float* pe   = (const float*)d_in[2];
    const float* te   = (const float*)d_in[3];
    const int*   tidx = (const int*)  d_in[4];
    float* out = (float*)d_out;

    // ws layout: pscr u64[B*HBA*KM] | alpha float4[B*KM] | enm,eden f32[B*KM] | scal f32[B*8]
    char* ws = (char*)d_ws;
    unsigned long long* pscr = (unsigned long long*)ws;
    float4* alpha = (float4*)(ws + (size_t)B * HBA * KM * 8);
    float*  enm   = (float*)(alpha + B * KM);
    float*  eden  = enm + B * KM;
    float*  scal  = eden + B * KM;
    const int NZ  = B * KM * 2 + B * 8;           // floats to zero (enm,eden,scal)
    const int NZB = (NZ + BLK - 1) / BLK;

    k_amax1<<<dim3(HBA, B), dim3(BLK), 0, stream>>>(beta, tidx, pscr, N, HBA);
    k_amax2<<<dim3(B * KM + NZB), dim3(BLK), 0, stream>>>(pscr, cc, alpha, enm, N, HBA, B, NZ);
    k_main<<<dim3(HBA, NCHUNK, B), dim3(BLK), 0, stream>>>(
        beta, cc, pe, te, tidx, alpha, enm, eden, scal, N);
    k_fin<<<dim3(1), dim3(BLK), 0, stream>>>(enm, eden, alpha, scal, out, N, B);
}

// Round 6
// 115.683 us; speedup vs baseline: 1.1390x; 1.1390x over previous
//
#include <hip/hip_runtime.h>
#include <math.h>

#define KM 192
#define NCHUNK 8
#define KCH (KM / NCHUNK)     // 24 objects per chunk
#define EPSF 1e-6f
#define QMIN 0.5f
#define BLK 256
#define H 4
#define TILE (BLK * H)        // 1024 hits per tile

__device__ __forceinline__ float clipb(float b) {
    return fminf(fmaxf(b, 1e-4f), 1.0f - 1e-4f);
}
// atanh(b) = 0.5*ln((1+b)/(1-b)) = (ln2/2)*log2((1+b)/(1-b)); b in [1e-4, 1-1e-4]
__device__ __forceinline__ float fast_atanh(float b) {
    float r = (1.f + b) * __builtin_amdgcn_rcpf(1.f - b);
    return 0.34657359f * __builtin_amdgcn_logf(r);
}

// ---- K1: per-tile argmax partials into scratch; block(0,0) zeroes accumulators ----
// pack = (bits(clip(beta)) << 32) | (N-1-i): beta>0 -> bits monotone; low word
// gives jnp.argmax first-index tiebreak. argmax(beta) == argmax(q) (monotone).
__global__ void __launch_bounds__(BLK)
k_amax(const float* __restrict__ beta, const int* __restrict__ tidx,
       unsigned long long* __restrict__ pscr, float* __restrict__ zf,
       unsigned int* __restrict__ cnt, int N, int HBA, int NZ) {
    const int e = blockIdx.y;
    __shared__ unsigned long long smax[KM];
    for (int k = threadIdx.x; k < KM; k += BLK) smax[k] = 0ull;
    __syncthreads();
    const size_t base = (size_t)e * N;
    #pragma unroll
    for (int h = 0; h < H; ++h) {
        int i = blockIdx.x * TILE + h * BLK + threadIdx.x;
        if (i < N) {
            int t = tidx[base + i];
            if (t > 0) {
                float bc = clipb(beta[base + i]);
                unsigned long long pack =
                    ((unsigned long long)__float_as_uint(bc) << 32) |
                    (unsigned long long)(unsigned)(N - 1 - i);
                atomicMax(&smax[t], pack);
            }
        }
    }
    __syncthreads();
    unsigned long long* row = pscr + ((size_t)e * HBA + blockIdx.x) * KM;
    for (int k = threadIdx.x; k < KM; k += BLK) row[k] = smax[k];

    if (blockIdx.x == 0 && blockIdx.y == 0) {       // zero enm/eden/scal + counter
        for (int z = threadIdx.x; z < NZ; z += BLK) zf[z] = 0.f;
        if (threadIdx.x == 0) cnt[0] = 0u;
    }
}

// ---- K2: chunk alpha-reduce (preamble) + main pass + last-block finalize ----
__global__ void __launch_bounds__(BLK, 4)
k_main(const float* __restrict__ beta, const float* __restrict__ cc,
       const float* __restrict__ pe,   const float* __restrict__ te,
       const int* __restrict__ tidx,   const unsigned long long* __restrict__ pscr,
       float* __restrict__ abw, float* __restrict__ enm, float* __restrict__ eden,
       float* __restrict__ scal, unsigned int* __restrict__ cnt,
       float* __restrict__ out, int N, int HBA, int B) {
    const int e = blockIdx.z, c = blockIdx.y, k0 = c * KCH;
    __shared__ float4 sa[KCH];                  // (x_a, y_a, q_a*valid, beta_a)
    __shared__ unsigned long long s8[KCH][8];
    __shared__ float sn[KM], sd[KM];
    __shared__ float sw[12];
    __shared__ int   lastFlag;

    // reduce this chunk's slots from pscr (L2-resident, ~300KB)
    if (threadIdx.x < KCH * 8) {
        const int j = threadIdx.x >> 3, l = threadIdx.x & 7;
        const unsigned long long* pk = pscr + (size_t)e * HBA * KM + (k0 + j);
        unsigned long long v = 0ull;
        for (int t = l; t < HBA; t += 8) {
            unsigned long long p = pk[(size_t)t * KM];
            if (p > v) v = p;
        }
        s8[j][l] = v;
    }
    for (int k = threadIdx.x; k < KM; k += BLK) { sn[k] = 0.f; sd[k] = 0.f; }
    __syncthreads();
    if (threadIdx.x < KCH) {
        unsigned long long v = 0ull;
        #pragma unroll
        for (int l = 0; l < 8; ++l) { unsigned long long p = s8[threadIdx.x][l]; if (p > v) v = p; }
        float4 a = make_float4(0.f, 0.f, 0.f, 0.f);
        if (v) {
            int idx  = N - 1 - (int)(unsigned)(v & 0xffffffffull);
            float bc = __uint_as_float((unsigned)(v >> 32));
            float at = fast_atanh(bc);
            float2 cp = ((const float2*)cc)[(size_t)e * N + idx];
            a = make_float4(cp.x, cp.y, fmaf(at, at, QMIN), bc);
        }
        sa[threadIdx.x] = a;
        if (blockIdx.x == 0) atomicExch(&abw[e * KM + k0 + threadIdx.x], a.w);
    }
    __syncthreads();

    const size_t base = (size_t)e * N;
    const int i0 = blockIdx.x * TILE + threadIdx.x;
    float ax[H], ay[H], qq[H], bcl[H]; int tt[H];
    #pragma unroll
    for (int h = 0; h < H; ++h) {
        int i = i0 + h * BLK;
        bool ok = i < N;
        int ii = ok ? i : 0;
        float2 cp = ((const float2*)cc)[base + ii];
        ax[h] = cp.x; ay[h] = cp.y;
        float bc = clipb(beta[base + ii]);
        bcl[h] = bc;
        float at = fast_atanh(bc);
        qq[h] = ok ? fmaf(at, at, QMIN) : 0.f;   // qq=0 kills pad-hit lv
        tt[h] = ok ? tidx[base + ii] : 0;
    }

    float acc[H] = {0.f, 0.f, 0.f, 0.f};
    #pragma unroll 6
    for (int k = 0; k < KCH; ++k) {
        float4 av = sa[k];
        #pragma unroll
        for (int h = 0; h < H; ++h) {
            float dx = ax[h] - av.x, dy = ay[h] - av.y;
            float d2 = fmaf(dx, dx, fmaf(dy, dy, EPSF));
            acc[h] = fmaf(fmaxf(1.f - __builtin_amdgcn_sqrtf(d2), 0.f), av.z, acc[h]);
        }
    }

    float lv = 0.f, bn = 0.f, cn = 0.f;
    #pragma unroll
    for (int h = 0; h < H; ++h) {
        float rep = acc[h], att = 0.f;
        int tl = tt[h] - k0;
        if (tt[h] > 0 && tl >= 0 && tl < KCH) {
            float4 ao = sa[tl];
            float dx = ax[h] - ao.x, dy = ay[h] - ao.y;
            float d2e = fmaf(dx, dx, fmaf(dy, dy, EPSF));
            rep -= fmaxf(1.f - __builtin_amdgcn_sqrtf(d2e), 0.f) * ao.z;
            att  = fmaf(dx, dx, dy * dy) * ao.z;
        }
        lv += qq[h] * (att + rep);
        if (c == 0) {
            int i = i0 + h * BLK;
            if (i < N) {
                if (tt[h] > 0) {
                    float tev = te[base + i];
                    float edv = (pe[base + i] - tev) / (tev + 1.f);
                    float ad  = fabsf(edv);
                    float eh  = (ad <= 2.f) ? 0.5f * ad * ad : 2.f * (ad - 1.f);
                    atomicAdd(&sn[tt[h]], bcl[h] * eh);
                    atomicAdd(&sd[tt[h]], bcl[h]);
                } else { bn += bcl[h]; cn += 1.f; }
            }
        }
    }
    __syncthreads();

    if (c == 0) {
        for (int k = threadIdx.x; k < KM; k += BLK) {
            float vd = sd[k];
            if (vd != 0.f) {
                atomicAdd(&enm [e * KM + k], sn[k]);
                atomicAdd(&eden[e * KM + k], vd);
            }
        }
    }
    for (int off = 32; off > 0; off >>= 1) {
        lv += __shfl_down(lv, off);
        bn += __shfl_down(bn, off);
        cn += __shfl_down(cn, off);
    }
    const int wid = threadIdx.x >> 6;
    if ((threadIdx.x & 63) == 0) { sw[wid] = lv; sw[4 + wid] = bn; sw[8 + wid] = cn; }
    __syncthreads();
    if (threadIdx.x == 0) {
        atomicAdd(&scal[e * 8 + 0], (sw[0] + sw[1]) + (sw[2] + sw[3]));
        if (c == 0) {
            atomicAdd(&scal[e * 8 + 3], (sw[4] + sw[5]) + (sw[6] + sw[7]));
            atomicAdd(&scal[e * 8 + 4], (sw[8] + sw[9]) + (sw[10] + sw[11]));
        }
    }

    // ---- last-block-done finalize ----
    if (threadIdx.x == 0) {
        __threadfence();
        unsigned int total = gridDim.x * gridDim.y * gridDim.z;
        unsigned int old = atomicAdd(cnt, 1u);
        lastFlag = (old == total - 1u);
    }
    __syncthreads();
    if (!lastFlag) return;
    __threadfence();

    volatile float* vab = abw;
    volatile float* ven = enm;
    volatile float* ved = eden;
    volatile float* vsc = scal;
    float tot = 0.f;
    for (int ev = 0; ev < B; ++ev) {
        float lb = 0.f, nv = 0.f, le = 0.f;
        for (int k = threadIdx.x; k < KM; k += BLK) {
            float bw = vab[ev * KM + k];
            if (bw > 0.f) {
                lb += 1.f - bw;
                nv += 1.f;
                le += ven[ev * KM + k] / (ved[ev * KM + k] + EPSF);
            }
        }
        for (int off = 32; off > 0; off >>= 1) {
            lb += __shfl_down(lb, off);
            nv += __shfl_down(nv, off);
            le += __shfl_down(le, off);
        }
        if ((threadIdx.x & 63) == 0) { sw[wid] = lb; sw[4 + wid] = nv; sw[8 + wid] = le; }
        __syncthreads();
        if (threadIdx.x == 0) {
            float lbs = (sw[0] + sw[1]) + (sw[2] + sw[3]);
            float nvs = (sw[4] + sw[5]) + (sw[6] + sw[7]);
            float les = (sw[8] + sw[9]) + (sw[10] + sw[11]);
            float nobj = nvs + EPSF;
            tot += vsc[ev * 8 + 0] / (float)N + lbs / nobj
                 + vsc[ev * 8 + 3] / (vsc[ev * 8 + 4] + EPSF) + les / nobj;
        }
        __syncthreads();
    }
    if (threadIdx.x == 0) out[0] = tot / (float)B;
}

extern "C" void kernel_launch(void* const* d_in, const int* in_sizes, int n_in,
                              void* d_out, int out_size, void* d_ws, size_t ws_size,
                              hipStream_t stream) {
    const int B = 4;
    const int N = in_sizes[0] / B;            // beta is [B,N,1]
    const int HBA = (N + TILE - 1) / TILE;    // tiles of 1024

    const float* beta = (const float*)d_in[0];
    const float* cc   = (const float*)d_in[1];
    const float* pe   = (const float*)d_in[2];
    const float* te   = (const float*)d_in[3];
    const int*   tidx = (const int*)  d_in[4];
    float* out = (float*)d_out;

    // ws: pscr u64[B*HBA*KM] | abw f32[B*KM] | enm f32[B*KM] | eden f32[B*KM]
    //     | scal f32[B*8] | cnt u32
    char* ws = (char*)d_ws;
    unsigned long long* pscr = (unsigned long long*)ws;
    float* abw  = (float*)(ws + (size_t)B * HBA * KM * 8);
    float* enm  = abw + B * KM;
    float* eden = enm + B * KM;
    float* scal = eden + B * KM;
    unsigned int* cnt = (unsigned int*)(scal + B * 8);
    const int NZ = B * KM * 2 + B * 8;        // enm+eden+scal floats (abw fully overwritten)

    k_amax<<<dim3(HBA, B), dim3(BLK), 0, stream>>>(beta, tidx, pscr, enm, cnt, N, HBA, NZ);
    k_main<<<dim3(HBA, NCHUNK, B), dim3(BLK), 0, stream>>>(
        beta, cc, pe, te, tidx, pscr, abw, enm, eden, scal, cnt, out, N, HBA, B);
}

// Round 7
// 98.988 us; speedup vs baseline: 1.3311x; 1.1686x over previous
//
#include <hip/hip_runtime.h>
#include <math.h>

#define KM 192
#define EPSF 1e-6f
#define QMIN 0.5f
#define BLKA 256
#define HA 4
#define TILEA (BLKA * HA)   // 1024 hits per argmax tile
#define BLKM 512

__device__ __forceinline__ float clipb(float b) {
    return fminf(fmaxf(b, 1e-4f), 1.0f - 1e-4f);
}
// atanh(b) = 0.5*ln((1+b)/(1-b)); b in [1e-4, 1-1e-4]
__device__ __forceinline__ float fast_atanh(float b) {
    float r = (1.f + b) * __builtin_amdgcn_rcpf(1.f - b);
    return 0.34657359f * __builtin_amdgcn_logf(r);
}

// ---- K1: per-tile argmax partials (no global atomics) ----
// pack = (bits(clip(beta)) << 32) | (N-1-i): beta>0 -> bits monotone; low word
// reproduces jnp.argmax first-index tiebreak. argmax(beta) == argmax(q).
__global__ void __launch_bounds__(BLKA)
k_amax(const float* __restrict__ beta, const int* __restrict__ tidx,
       unsigned long long* __restrict__ pscr, int N, int HBT) {
    const int e = blockIdx.y;
    __shared__ unsigned long long smax[KM];
    for (int k = threadIdx.x; k < KM; k += BLKA) smax[k] = 0ull;
    __syncthreads();
    const size_t base = (size_t)e * N;
    #pragma unroll
    for (int h = 0; h < HA; ++h) {
        int i = blockIdx.x * TILEA + h * BLKA + threadIdx.x;
        if (i < N) {
            int t = tidx[base + i];
            if (t > 0) {
                float bc = clipb(beta[base + i]);
                unsigned long long pack =
                    ((unsigned long long)__float_as_uint(bc) << 32) |
                    (unsigned long long)(unsigned)(N - 1 - i);
                atomicMax(&smax[t], pack);
            }
        }
    }
    __syncthreads();
    unsigned long long* row = pscr + ((size_t)e * HBT + blockIdx.x) * KM;
    for (int k = threadIdx.x; k < KM; k += BLKA) row[k] = smax[k];
}

// ---- K2: build alpha table (x, y, q_a*valid, x^2+y^2+eps) + beta_alpha;
//          zero enm/eden/scal/cnt. 4 blocks (one per event). ----
__global__ void __launch_bounds__(256)
k_alpha(const unsigned long long* __restrict__ pscr, const float* __restrict__ cc,
        float4* __restrict__ alpha, float* __restrict__ abw,
        float* __restrict__ enm, float* __restrict__ eden,
        float* __restrict__ scal, unsigned int* __restrict__ cnt,
        int N, int HBT) {
    const int e = blockIdx.x;
    const int k = threadIdx.x;
    if (k < KM) {
        const unsigned long long* pk = pscr + (size_t)e * HBT * KM + k;
        unsigned long long v = 0ull;
        #pragma unroll 8
        for (int t = 0; t < HBT; ++t) {
            unsigned long long p = pk[(size_t)t * KM];
            if (p > v) v = p;
        }
        float4 a = make_float4(0.f, 0.f, 0.f, EPSF);
        float bw = 0.f;
        if (v) {
            int idx = N - 1 - (int)(unsigned)(v & 0xffffffffull);
            bw = __uint_as_float((unsigned)(v >> 32));     // clipped beta_alpha
            float at = fast_atanh(bw);
            float2 cp = ((const float2*)cc)[(size_t)e * N + idx];
            a.x = cp.x; a.y = cp.y;
            a.z = fmaf(at, at, QMIN);                      // q_alpha (0 => invalid)
            a.w = fmaf(cp.x, cp.x, fmaf(cp.y, cp.y, EPSF)); // aa + eps
        }
        alpha[e * KM + k] = a;
        abw  [e * KM + k] = bw;
    }
    for (int z = threadIdx.x; z < KM; z += 256) {
        enm [e * KM + z] = 0.f;
        eden[e * KM + z] = 0.f;
    }
    if (threadIdx.x < 8) scal[e * 8 + threadIdx.x] = 0.f;
    if (blockIdx.x == 0 && threadIdx.x == 0) cnt[0] = 0u;
}

// ---- K3: main pass (full K per hit, uniform alpha loads) + last-block finalize ----
__global__ void __launch_bounds__(BLKM)
k_main(const float* __restrict__ beta, const float* __restrict__ cc,
       const float* __restrict__ pe,   const float* __restrict__ te,
       const int* __restrict__ tidx,   const float4* __restrict__ alpha,
       const float* __restrict__ abw,
       float* __restrict__ enm, float* __restrict__ eden,
       float* __restrict__ scal, unsigned int* __restrict__ cnt,
       float* __restrict__ out, int N, int B) {
    const int e = blockIdx.y;
    __shared__ float sn[KM], sd[KM];
    __shared__ float sw[24];
    __shared__ int   lastFlag;
    for (int k = threadIdx.x; k < KM; k += BLKM) { sn[k] = 0.f; sd[k] = 0.f; }
    __syncthreads();

    const size_t base = (size_t)e * N;
    const int i = blockIdx.x * BLKM + threadIdx.x;
    const bool ok = i < N;
    const size_t ii = base + (ok ? i : 0);
    float2 cp = ((const float2*)cc)[ii];
    float  bc = clipb(beta[ii]);
    int    t  = ok ? tidx[ii] : 0;
    float  at = fast_atanh(bc);
    float  qq = ok ? fmaf(at, at, QMIN) : 0.f;   // qq=0 kills pad-hit lv
    float  pp = fmaf(cp.x, cp.x, cp.y * cp.y);

    // repulsive hinge over all objects; alpha loads are wave-uniform (s_load)
    const float4* __restrict__ ae = alpha + e * KM;
    float r0 = 0.f, r1 = 0.f, r2 = 0.f, r3 = 0.f;
    for (int k = 0; k < KM; k += 4) {
        float4 a0 = ae[k], a1 = ae[k + 1], a2 = ae[k + 2], a3 = ae[k + 3];
        // d2+eps = pp + (aa+eps) - 2*dot(p, a)
        float d0 = fmaf(-2.f, fmaf(cp.x, a0.x, cp.y * a0.y), pp + a0.w);
        float d1 = fmaf(-2.f, fmaf(cp.x, a1.x, cp.y * a1.y), pp + a1.w);
        float d2 = fmaf(-2.f, fmaf(cp.x, a2.x, cp.y * a2.y), pp + a2.w);
        float d3 = fmaf(-2.f, fmaf(cp.x, a3.x, cp.y * a3.y), pp + a3.w);
        r0 = fmaf(fmaxf(1.f - __builtin_amdgcn_sqrtf(d0), 0.f), a0.z, r0);
        r1 = fmaf(fmaxf(1.f - __builtin_amdgcn_sqrtf(d1), 0.f), a1.z, r1);
        r2 = fmaf(fmaxf(1.f - __builtin_amdgcn_sqrtf(d2), 0.f), a2.z, r2);
        r3 = fmaf(fmaxf(1.f - __builtin_amdgcn_sqrtf(d3), 0.f), a3.z, r3);
    }
    float rep = (r0 + r1) + (r2 + r3);
    float att = 0.f, lv = 0.f, bn = 0.f, cn = 0.f;

    if (t > 0) {                        // t>0 implies ok (pad hits have t=0)
        float4 av = ae[t];              // divergent, L1-resident (3KB table)
        float dx = cp.x - av.x, dy = cp.y - av.y;
        float d2 = fmaf(dx, dx, dy * dy);
        att = d2 * av.z;
        rep -= fmaxf(1.f - __builtin_amdgcn_sqrtf(d2 + EPSF), 0.f) * av.z;
        float tev = te[ii];
        float edv = (pe[ii] - tev) * __builtin_amdgcn_rcpf(tev + 1.f);
        float ad  = fabsf(edv);
        float eh  = (ad <= 2.f) ? 0.5f * ad * ad : 2.f * (ad - 1.f);
        atomicAdd(&sn[t], bc * eh);
        atomicAdd(&sd[t], bc);
    } else if (ok) { bn = bc; cn = 1.f; }
    lv = qq * (att + rep);
    __syncthreads();

    if (threadIdx.x < KM) {
        float vd = sd[threadIdx.x];
        if (vd != 0.f) {
            atomicAdd(&enm [e * KM + threadIdx.x], sn[threadIdx.x]);
            atomicAdd(&eden[e * KM + threadIdx.x], vd);
        }
    }
    for (int off = 32; off > 0; off >>= 1) {
        lv += __shfl_down(lv, off);
        bn += __shfl_down(bn, off);
        cn += __shfl_down(cn, off);
    }
    const int wid = threadIdx.x >> 6;
    if ((threadIdx.x & 63) == 0) { sw[wid] = lv; sw[8 + wid] = bn; sw[16 + wid] = cn; }
    __syncthreads();
    if (threadIdx.x == 0) {
        float a = 0.f, b2 = 0.f, c2 = 0.f;
        #pragma unroll
        for (int w = 0; w < 8; ++w) { a += sw[w]; b2 += sw[8 + w]; c2 += sw[16 + w]; }
        atomicAdd(&scal[e * 8 + 0], a);
        atomicAdd(&scal[e * 8 + 3], b2);
        atomicAdd(&scal[e * 8 + 4], c2);
    }

    // ---- last-block-done finalize ----
    if (threadIdx.x == 0) {
        __threadfence();
        unsigned int old = atomicAdd(cnt, 1u);
        lastFlag = (old == gridDim.x * gridDim.y - 1u);
    }
    __syncthreads();
    if (!lastFlag) return;
    __threadfence();

    volatile float* ven = enm;
    volatile float* ved = eden;
    volatile float* vsc = scal;
    float tot = 0.f;
    for (int ev = 0; ev < B; ++ev) {
        float lb = 0.f, nv = 0.f, le = 0.f;
        if (threadIdx.x < KM) {
            float bw = abw[ev * KM + threadIdx.x];
            if (bw > 0.f) {
                lb = 1.f - bw;
                nv = 1.f;
                le = ven[ev * KM + threadIdx.x] / (ved[ev * KM + threadIdx.x] + EPSF);
            }
        }
        for (int off = 32; off > 0; off >>= 1) {
            lb += __shfl_down(lb, off);
            nv += __shfl_down(nv, off);
            le += __shfl_down(le, off);
        }
        if ((threadIdx.x & 63) == 0) { sw[wid] = lb; sw[8 + wid] = nv; sw[16 + wid] = le; }
        __syncthreads();
        if (threadIdx.x == 0) {
            float lbs = 0.f, nvs = 0.f, les = 0.f;
            #pragma unroll
            for (int w = 0; w < 8; ++w) { lbs += sw[w]; nvs += sw[8 + w]; les += sw[16 + w]; }
            float nobj = nvs + EPSF;
            tot += vsc[ev * 8 + 0] / (float)N + lbs / nobj
                 + vsc[ev * 8 + 3] / (vsc[ev * 8 + 4] + EPSF) + les / nobj;
        }
        __syncthreads();
    }
    if (threadIdx.x == 0) out[0] = tot / (float)B;
}

extern "C" void kernel_launch(void* const* d_in, const int* in_sizes, int n_in,
                              void* d_out, int out_size, void* d_ws, size_t ws_size,
                              hipStream_t stream) {
    const int B = 4;
    const int N = in_sizes[0] / B;               // beta is [B,N,1]
    const int HBT = (N + TILEA - 1) / TILEA;     // argmax tiles of 1024
    const int MB  = (N + BLKM - 1) / BLKM;       // main tiles of 512

    const float* beta = (const float*)d_in[0];
    const float* cc   = (const float*)d_in[1];
    const float* pe   = (const float*)d_in[2];
    const float* te   = (const float*)d_in[3];
    const int*   tidx = (const int*)  d_in[4];
    float* out = (float*)d_out;

    // ws: pscr u64[B*HBT*KM] | alpha float4[B*KM] | abw f32[B*KM]
    //     | enm f32[B*KM] | eden f32[B*KM] | scal f32[B*8] | cnt u32
    char* ws = (char*)d_ws;
    unsigned long long* pscr = (unsigned long long*)ws;
    float4* alpha = (float4*)(ws + (size_t)B * HBT * KM * 8);
    float*  abw   = (float*)(alpha + B * KM);
    float*  enm   = abw  + B * KM;
    float*  eden  = enm  + B * KM;
    float*  scal  = eden + B * KM;
    unsigned int* cnt = (unsigned int*)(scal + B * 8);

    k_amax<<<dim3(HBT, B), dim3(BLKA), 0, stream>>>(beta, tidx, pscr, N, HBT);
    k_alpha<<<dim3(B), dim3(256), 0, stream>>>(pscr, cc, alpha, abw, enm, eden, scal, cnt, N, HBT);
    k_main<<<dim3(MB, B), dim3(BLKM), 0, stream>>>(
        beta, cc, pe, te, tidx, alpha, abw, enm, eden, scal, cnt, out, N, B);
}